// Round 1
// baseline (1618.395 us; speedup 1.0000x reference)
//
#include <hip/hip_runtime.h>

#define N_NODES 50000
#define N_EDGES 800000
#define IN_DIM 128
#define HID_DIM 256
#define OUT_DIM 2
#define NODE_TILE 32

// ---------------------------------------------------------------------------
// Step 2: scatter-add x[src] rows into agg1[dst].  32 threads per edge, each
// handling a float4 chunk (coalesced 512B row reads).
// ---------------------------------------------------------------------------
__global__ __launch_bounds__(256) void k_scatter_x(
    const float* __restrict__ x, const int* __restrict__ ei,
    float* __restrict__ agg1)
{
    long long idx = (long long)blockIdx.x * 256 + threadIdx.x;
    if (idx >= (long long)N_EDGES * 32) return;
    int e = (int)(idx >> 5);
    int c = ((int)idx & 31) << 2;
    int src = ei[e];
    int dst = ei[N_EDGES + e];
    float4 v = *(const float4*)(x + (size_t)src * IN_DIM + c);
    float* o = agg1 + (size_t)dst * IN_DIM + c;
    atomicAdd(o + 0, v.x);
    atomicAdd(o + 1, v.y);
    atomicAdd(o + 2, v.z);
    atomicAdd(o + 3, v.w);
}

// ---------------------------------------------------------------------------
// Step 3: fused   h = relu(((1+e1)x + agg1) @ W1 + b1);  p = h @ W2
//         out_init = (1+e2)*p + b2
// Block = 256 threads, 32-node tile. Thread j owns output column j of W1.
// z staged in LDS (broadcast reads), W1 loaded coalesced per k-row.
// ---------------------------------------------------------------------------
__global__ __launch_bounds__(256) void k_fused_mlp(
    const float* __restrict__ x, const float* __restrict__ agg1,
    const float* __restrict__ W1, const float* __restrict__ b1,
    const float* __restrict__ W2, const float* __restrict__ b2,
    const float* __restrict__ eps1p, const float* __restrict__ eps2p,
    float* __restrict__ p, float* __restrict__ out_init)
{
    __shared__ float z[NODE_TILE][IN_DIM];          // 16 KB
    __shared__ float hl[NODE_TILE][HID_DIM + 1];    // padded: +1 kills 32-way
                                                    // bank conflict in p-loop
    const int tid = threadIdx.x;
    const int node0 = blockIdx.x * NODE_TILE;
    const float e1 = 1.0f + eps1p[0];

    // stage z = (1+eps1)*x + agg1 for the 32-node tile (float4 loads)
    for (int i = tid; i < NODE_TILE * (IN_DIM / 4); i += 256) {
        int n = i / (IN_DIM / 4);
        int c = i % (IN_DIM / 4);
        int node = node0 + n;
        float4 zv = make_float4(0.f, 0.f, 0.f, 0.f);
        if (node < N_NODES) {
            float4 xv = ((const float4*)(x + (size_t)node * IN_DIM))[c];
            float4 av = ((const float4*)(agg1 + (size_t)node * IN_DIM))[c];
            zv.x = fmaf(e1, xv.x, av.x);
            zv.y = fmaf(e1, xv.y, av.y);
            zv.z = fmaf(e1, xv.z, av.z);
            zv.w = fmaf(e1, xv.w, av.w);
        }
        ((float4*)&z[n][0])[c] = zv;
    }
    __syncthreads();

    // GEMM1: thread tid = column j of W1; 32 accumulators (one per node)
    float acc[NODE_TILE];
#pragma unroll
    for (int n = 0; n < NODE_TILE; n++) acc[n] = b1[tid];

    for (int k4 = 0; k4 < IN_DIM / 4; k4++) {
        float4 w;
        w.x = W1[(4 * k4 + 0) * HID_DIM + tid];
        w.y = W1[(4 * k4 + 1) * HID_DIM + tid];
        w.z = W1[(4 * k4 + 2) * HID_DIM + tid];
        w.w = W1[(4 * k4 + 3) * HID_DIM + tid];
#pragma unroll
        for (int n = 0; n < NODE_TILE; n++) {
            float4 zv = *(const float4*)&z[n][4 * k4];
            acc[n] = fmaf(zv.x, w.x,
                     fmaf(zv.y, w.y,
                     fmaf(zv.z, w.z,
                     fmaf(zv.w, w.w, acc[n]))));
        }
    }

    // ReLU into padded LDS
#pragma unroll
    for (int n = 0; n < NODE_TILE; n++)
        hl[n][tid] = fmaxf(acc[n], 0.0f);
    __syncthreads();

    // GEMM2: 64 threads -> (node, outdim) pairs; bank-conflict-free via pad
    if (tid < NODE_TILE * OUT_DIM) {
        int n = tid / OUT_DIM;
        int d = tid % OUT_DIM;
        int node = node0 + n;
        if (node < N_NODES) {
            float s = 0.0f;
            for (int j = 0; j < HID_DIM; j++)
                s = fmaf(hl[n][j], W2[j * OUT_DIM + d], s);
            p[(size_t)node * OUT_DIM + d] = s;
            float e2 = 1.0f + eps2p[0];
            out_init[(size_t)node * OUT_DIM + d] = fmaf(e2, s, b2[d]);
        }
    }
}

// ---------------------------------------------------------------------------
// Step 4: out[dst] += p[src]   (2 floats per edge)
// ---------------------------------------------------------------------------
__global__ __launch_bounds__(256) void k_scatter_p(
    const int* __restrict__ ei, const float* __restrict__ p,
    float* __restrict__ out)
{
    int e = blockIdx.x * 256 + threadIdx.x;
    if (e >= N_EDGES) return;
    int src = ei[e];
    int dst = ei[N_EDGES + e];
    float2 v = *(const float2*)(p + (size_t)src * OUT_DIM);
    atomicAdd(out + (size_t)dst * OUT_DIM + 0, v.x);
    atomicAdd(out + (size_t)dst * OUT_DIM + 1, v.y);
}

extern "C" void kernel_launch(void* const* d_in, const int* in_sizes, int n_in,
                              void* d_out, int out_size, void* d_ws, size_t ws_size,
                              hipStream_t stream)
{
    const float* x    = (const float*)d_in[0];
    const int*   ei   = (const int*)d_in[1];   // [2, N_EDGES] flattened
    const float* W1   = (const float*)d_in[2];
    const float* b1   = (const float*)d_in[3];
    const float* W2   = (const float*)d_in[4];
    const float* b2   = (const float*)d_in[5];
    const float* eps1 = (const float*)d_in[6];
    const float* eps2 = (const float*)d_in[7];
    float* out = (float*)d_out;

    // workspace layout: agg1 [N_NODES*IN_DIM] fp32, then p [N_NODES*OUT_DIM]
    float* agg1 = (float*)d_ws;
    float* p    = agg1 + (size_t)N_NODES * IN_DIM;

    hipMemsetAsync(agg1, 0, (size_t)N_NODES * IN_DIM * sizeof(float), stream);

    {
        long long total = (long long)N_EDGES * 32;
        int blocks = (int)((total + 255) / 256);
        k_scatter_x<<<blocks, 256, 0, stream>>>(x, ei, agg1);
    }
    {
        int blocks = (N_NODES + NODE_TILE - 1) / NODE_TILE;
        k_fused_mlp<<<blocks, 256, 0, stream>>>(x, agg1, W1, b1, W2, b2,
                                                eps1, eps2, p, out);
    }
    {
        int blocks = (N_EDGES + 255) / 256;
        k_scatter_p<<<blocks, 256, 0, stream>>>(ei, p, out);
    }
}

// Round 2
// 343.112 us; speedup vs baseline: 4.7168x; 4.7168x over previous
//
#include <hip/hip_runtime.h>

#define N_NODES 50000
#define N_EDGES 800000
#define IN_DIM 128
#define HID_DIM 256
#define OUT_DIM 2
#define NODE_TILE 32   // nodes per block in k_gin1 (8 per wave)

// ---------------------------------------------------------------------------
// CSR build step 1: in-degree histogram
// ---------------------------------------------------------------------------
__global__ __launch_bounds__(256) void k_hist(const int* __restrict__ ei,
                                              int* __restrict__ deg)
{
    int e = blockIdx.x * 256 + threadIdx.x;
    if (e < N_EDGES) atomicAdd(&deg[ei[N_EDGES + e]], 1);
}

// ---------------------------------------------------------------------------
// CSR build step 2: exclusive scan of deg -> row_ptr (and cursor copy).
// Single workgroup of 1024 threads, 49 passes of 1024.
// ---------------------------------------------------------------------------
__global__ __launch_bounds__(1024) void k_scan(const int* __restrict__ deg,
                                               int* __restrict__ row_ptr,
                                               int* __restrict__ cursor)
{
    __shared__ int wsum[16];
    __shared__ int carry_s;
    const int tid  = threadIdx.x;
    const int lane = tid & 63;
    const int wave = tid >> 6;
    if (tid == 0) carry_s = 0;
    __syncthreads();

    for (int base = 0; base < N_NODES; base += 1024) {
        int i = base + tid;
        int v = (i < N_NODES) ? deg[i] : 0;
        // wave-inclusive scan
        int s = v;
        for (int off = 1; off < 64; off <<= 1) {
            int t = __shfl_up(s, off, 64);
            if (lane >= off) s += t;
        }
        if (lane == 63) wsum[wave] = s;
        __syncthreads();
        if (wave == 0) {
            int ws = (lane < 16) ? wsum[lane] : 0;
            for (int off = 1; off < 16; off <<= 1) {
                int t = __shfl_up(ws, off, 64);
                if (lane >= off) ws += t;
            }
            if (lane < 16) wsum[lane] = ws;   // inclusive wave sums
        }
        __syncthreads();
        int wave_excl = (wave == 0) ? 0 : wsum[wave - 1];
        int excl = carry_s + wave_excl + (s - v);
        if (i < N_NODES) { row_ptr[i] = excl; cursor[i] = excl; }
        __syncthreads();                        // all reads of carry_s/wsum done
        if (tid == 0) carry_s += wsum[15];
        __syncthreads();
    }
    if (tid == 0) row_ptr[N_NODES] = carry_s;   // == N_EDGES
}

// ---------------------------------------------------------------------------
// CSR build step 3: bucket src indices by dst
// ---------------------------------------------------------------------------
__global__ __launch_bounds__(256) void k_reorder(const int* __restrict__ ei,
                                                 int* __restrict__ cursor,
                                                 int* __restrict__ csr_src)
{
    int e = blockIdx.x * 256 + threadIdx.x;
    if (e < N_EDGES) {
        int dst = ei[N_EDGES + e];
        int pos = atomicAdd(&cursor[dst], 1);
        csr_src[pos] = ei[e];
    }
}

// ---------------------------------------------------------------------------
// Fused layer 1: pull-aggregate + z = (1+e1)x + agg  ->  GEMM1+ReLU -> GEMM2
// Block = 256 threads (4 waves), 32 nodes (8 per wave, wave-private).
// GEMM1: thread owns 4 columns (4*lane..4*lane+3); z broadcast from LDS,
//        4x register reuse per ds_read vs R1.
// GEMM2: in registers + shfl butterfly (no LDS).
// ---------------------------------------------------------------------------
__global__ __launch_bounds__(256) void k_gin1(
    const float* __restrict__ x, const int* __restrict__ row_ptr,
    const int* __restrict__ csr_src,
    const float* __restrict__ W1, const float* __restrict__ b1,
    const float* __restrict__ W2,
    const float* __restrict__ eps1p,
    float* __restrict__ p)
{
    __shared__ float z[NODE_TILE][IN_DIM];   // 16 KB
    const int tid   = threadIdx.x;
    const int lane  = tid & 63;
    const int wave  = tid >> 6;
    const int node0 = blockIdx.x * NODE_TILE;
    const float e1  = 1.0f + eps1p[0];

    // ---- Phase A: gather-sum neighbors for this wave's 8 nodes ----
    for (int nn = 0; nn < 8; nn++) {
        int node = node0 + 8 * wave + nn;
        float2 acc = make_float2(0.f, 0.f);
        if (node < N_NODES) {
            int beg = row_ptr[node];
            int end = row_ptr[node + 1];
#pragma unroll 4
            for (int e = beg; e < end; e++) {
                int src = csr_src[e];
                float2 v = *(const float2*)(x + (size_t)src * IN_DIM + 2 * lane);
                acc.x += v.x; acc.y += v.y;
            }
            float2 xv = *(const float2*)(x + (size_t)node * IN_DIM + 2 * lane);
            acc.x = fmaf(e1, xv.x, acc.x);
            acc.y = fmaf(e1, xv.y, acc.y);
        }
        *(float2*)&z[8 * wave + nn][2 * lane] = acc;
    }
    __syncthreads();

    // ---- Phase B: GEMM1 — 8 nodes x 4 columns per thread ----
    float4 b1v = *(const float4*)(b1 + 4 * lane);
    float4 acc[8];
#pragma unroll
    for (int nn = 0; nn < 8; nn++) acc[nn] = b1v;

    for (int k4 = 0; k4 < IN_DIM / 4; k4++) {
        float4 w0 = *(const float4*)(W1 + (size_t)(4 * k4 + 0) * HID_DIM + 4 * lane);
        float4 w1 = *(const float4*)(W1 + (size_t)(4 * k4 + 1) * HID_DIM + 4 * lane);
        float4 w2 = *(const float4*)(W1 + (size_t)(4 * k4 + 2) * HID_DIM + 4 * lane);
        float4 w3 = *(const float4*)(W1 + (size_t)(4 * k4 + 3) * HID_DIM + 4 * lane);
#pragma unroll
        for (int nn = 0; nn < 8; nn++) {
            float4 zv = *(const float4*)&z[8 * wave + nn][4 * k4];
            acc[nn].x = fmaf(zv.x, w0.x, fmaf(zv.y, w1.x, fmaf(zv.z, w2.x, fmaf(zv.w, w3.x, acc[nn].x))));
            acc[nn].y = fmaf(zv.x, w0.y, fmaf(zv.y, w1.y, fmaf(zv.z, w2.y, fmaf(zv.w, w3.y, acc[nn].y))));
            acc[nn].z = fmaf(zv.x, w0.z, fmaf(zv.y, w1.z, fmaf(zv.z, w2.z, fmaf(zv.w, w3.z, acc[nn].z))));
            acc[nn].w = fmaf(zv.x, w0.w, fmaf(zv.y, w1.w, fmaf(zv.z, w2.w, fmaf(zv.w, w3.w, acc[nn].w))));
        }
    }

    // ---- Phase C: ReLU + GEMM2 (thread holds columns 4l..4l+3) ----
    float2 w2v0 = *(const float2*)(W2 + (size_t)(4 * lane + 0) * OUT_DIM);
    float2 w2v1 = *(const float2*)(W2 + (size_t)(4 * lane + 1) * OUT_DIM);
    float2 w2v2 = *(const float2*)(W2 + (size_t)(4 * lane + 2) * OUT_DIM);
    float2 w2v3 = *(const float2*)(W2 + (size_t)(4 * lane + 3) * OUT_DIM);

#pragma unroll
    for (int nn = 0; nn < 8; nn++) {
        float h0 = fmaxf(acc[nn].x, 0.f);
        float h1 = fmaxf(acc[nn].y, 0.f);
        float h2 = fmaxf(acc[nn].z, 0.f);
        float h3 = fmaxf(acc[nn].w, 0.f);
        float px = h0 * w2v0.x + h1 * w2v1.x + h2 * w2v2.x + h3 * w2v3.x;
        float py = h0 * w2v0.y + h1 * w2v1.y + h2 * w2v2.y + h3 * w2v3.y;
        // wave butterfly reduction
#pragma unroll
        for (int off = 32; off >= 1; off >>= 1) {
            px += __shfl_xor(px, off, 64);
            py += __shfl_xor(py, off, 64);
        }
        int node = node0 + 8 * wave + nn;
        if (lane == 0 && node < N_NODES) {
            p[(size_t)node * OUT_DIM + 0] = px;
            p[(size_t)node * OUT_DIM + 1] = py;
        }
    }
}

// ---------------------------------------------------------------------------
// Layer 2 pull: out[n] = (1+e2)*p[n] + b2 + sum_{e in CSR row n} p[src]
// ---------------------------------------------------------------------------
__global__ __launch_bounds__(256) void k_out(
    const int* __restrict__ row_ptr, const int* __restrict__ csr_src,
    const float* __restrict__ p, const float* __restrict__ b2,
    const float* __restrict__ eps2p, float* __restrict__ out)
{
    int n = blockIdx.x * 256 + threadIdx.x;
    if (n >= N_NODES) return;
    float e2 = 1.0f + eps2p[0];
    int beg = row_ptr[n], end = row_ptr[n + 1];
    float sx = 0.f, sy = 0.f;
#pragma unroll 4
    for (int e = beg; e < end; e++) {
        int src = csr_src[e];
        float2 v = *(const float2*)(p + (size_t)src * OUT_DIM);
        sx += v.x; sy += v.y;
    }
    float2 pv = *(const float2*)(p + (size_t)n * OUT_DIM);
    out[(size_t)n * OUT_DIM + 0] = fmaf(e2, pv.x, sx) + b2[0];
    out[(size_t)n * OUT_DIM + 1] = fmaf(e2, pv.y, sy) + b2[1];
}

extern "C" void kernel_launch(void* const* d_in, const int* in_sizes, int n_in,
                              void* d_out, int out_size, void* d_ws, size_t ws_size,
                              hipStream_t stream)
{
    const float* x    = (const float*)d_in[0];
    const int*   ei   = (const int*)d_in[1];   // [2, N_EDGES] flat
    const float* W1   = (const float*)d_in[2];
    const float* b1   = (const float*)d_in[3];
    const float* W2   = (const float*)d_in[4];
    const float* b2   = (const float*)d_in[5];
    const float* eps1 = (const float*)d_in[6];
    const float* eps2 = (const float*)d_in[7];
    float* out = (float*)d_out;

    // workspace layout (all 16B aligned)
    int* deg     = (int*)d_ws;             // 50000 (padded 50048)
    int* row_ptr = deg + 50048;            // 50001 (padded 50056)
    int* cursor  = row_ptr + 50056;        // 50000 (padded 50048)
    int* csr_src = cursor + 50048;         // 800000
    float* p     = (float*)(csr_src + 800000);  // 100000

    hipMemsetAsync(deg, 0, 50000 * sizeof(int), stream);

    k_hist<<<(N_EDGES + 255) / 256, 256, 0, stream>>>(ei, deg);
    k_scan<<<1, 1024, 0, stream>>>(deg, row_ptr, cursor);
    k_reorder<<<(N_EDGES + 255) / 256, 256, 0, stream>>>(ei, cursor, csr_src);
    k_gin1<<<(N_NODES + NODE_TILE - 1) / NODE_TILE, 256, 0, stream>>>(
        x, row_ptr, csr_src, W1, b1, W2, eps1, p);
    k_out<<<(N_NODES + 255) / 256, 256, 0, stream>>>(row_ptr, csr_src, p, b2, eps2, out);
}

// Round 3
// 327.806 us; speedup vs baseline: 4.9370x; 1.0467x over previous
//
#include <hip/hip_runtime.h>

#define N_NODES 50000
#define N_EDGES 800000
#define IN_DIM 128
#define HID_DIM 256
#define OUT_DIM 2

#define NT   32   // nodes per block in k_gin1
#define NPW  16   // nodes per wave (2 waves/block)

// ---------------------------------------------------------------------------
// x (fp32) -> packed bf16x2 (RNE).  uint i holds cols {2i%128, 2i%128+1}.
// ---------------------------------------------------------------------------
__global__ __launch_bounds__(256) void k_cvt(const float* __restrict__ x,
                                             unsigned* __restrict__ xb)
{
    int i = blockIdx.x * 256 + threadIdx.x;
    if (i < N_NODES * IN_DIM / 2) {
        float2 v = ((const float2*)x)[i];
        unsigned lo = __float_as_uint(v.x);
        unsigned hi = __float_as_uint(v.y);
        lo = (lo + 0x7fffu + ((lo >> 16) & 1u)) >> 16;
        hi = (hi + 0x7fffu + ((hi >> 16) & 1u)) >> 16;
        xb[i] = (hi << 16) | lo;
    }
}

// ---------------------------------------------------------------------------
// CSR build: histogram -> 3-step parallel scan -> reorder
// ---------------------------------------------------------------------------
__global__ __launch_bounds__(256) void k_hist(const int* __restrict__ ei,
                                              int* __restrict__ deg)
{
    int e = blockIdx.x * 256 + threadIdx.x;
    if (e < N_EDGES) atomicAdd(&deg[ei[N_EDGES + e]], 1);
}

__global__ __launch_bounds__(256) void k_scan_blk(const int* __restrict__ deg,
                                                  int* __restrict__ row_ptr,
                                                  int* __restrict__ partials)
{
    __shared__ int wsum[4];
    const int tid = threadIdx.x, lane = tid & 63, wave = tid >> 6;
    int i = blockIdx.x * 256 + tid;
    int v = (i < N_NODES) ? deg[i] : 0;
    int s = v;
#pragma unroll
    for (int off = 1; off < 64; off <<= 1) {
        int t = __shfl_up(s, off, 64);
        if (lane >= off) s += t;
    }
    if (lane == 63) wsum[wave] = s;
    __syncthreads();
    int wexcl = 0;
    for (int w = 0; w < wave; w++) wexcl += wsum[w];
    if (i < N_NODES) row_ptr[i] = wexcl + s - v;   // exclusive within block
    if (tid == 255) partials[blockIdx.x] = wexcl + s;
}

__global__ __launch_bounds__(256) void k_scan_top(const int* __restrict__ partials,
                                                  int* __restrict__ offsets,
                                                  int nblk)
{
    __shared__ int wsum[4];
    const int tid = threadIdx.x, lane = tid & 63, wave = tid >> 6;
    int v = (tid < nblk) ? partials[tid] : 0;
    int s = v;
#pragma unroll
    for (int off = 1; off < 64; off <<= 1) {
        int t = __shfl_up(s, off, 64);
        if (lane >= off) s += t;
    }
    if (lane == 63) wsum[wave] = s;
    __syncthreads();
    int wexcl = 0;
    for (int w = 0; w < wave; w++) wexcl += wsum[w];
    offsets[tid] = wexcl + s - v;                  // exclusive block offsets
}

__global__ __launch_bounds__(256) void k_scan_add(int* __restrict__ row_ptr,
                                                  const int* __restrict__ offsets,
                                                  int* __restrict__ cursor)
{
    int i = blockIdx.x * 256 + threadIdx.x;
    if (i < N_NODES) {
        int r = row_ptr[i] + offsets[blockIdx.x];
        row_ptr[i] = r;
        cursor[i]  = r;
    }
    if (i == 0) row_ptr[N_NODES] = N_EDGES;
}

__global__ __launch_bounds__(256) void k_reorder(const int* __restrict__ ei,
                                                 int* __restrict__ cursor,
                                                 int* __restrict__ csr_src)
{
    int e = blockIdx.x * 256 + threadIdx.x;
    if (e < N_EDGES) {
        int dst = ei[N_EDGES + e];
        int pos = atomicAdd(&cursor[dst], 1);
        csr_src[pos] = ei[e];
    }
}

// ---------------------------------------------------------------------------
// Fused layer 1: bf16 pull-aggregate -> z=(1+e1)x+agg -> GEMM1+ReLU -> GEMM2
// 128 threads = 2 waves, 16 nodes per wave, NO cross-wave sharing, no barrier.
// Phase A: lane-parallel csr_src prefetch (1 coalesced load per 64 edges),
//          8 bf16x2 row-loads in flight, fp32 accumulate.
// Phase B: thread owns 4 W1 columns; z broadcast-read from LDS (uniform addr).
// Phase C: ReLU + W2 dot in registers + 64-lane butterfly.
// ---------------------------------------------------------------------------
__global__ __launch_bounds__(128) void k_gin1(
    const float* __restrict__ x, const unsigned* __restrict__ xb,
    const int* __restrict__ row_ptr, const int* __restrict__ csr_src,
    const float* __restrict__ W1, const float* __restrict__ b1,
    const float* __restrict__ W2, const float* __restrict__ eps1p,
    float* __restrict__ p)
{
    __shared__ float z[NT][IN_DIM];   // 16 KB
    const int tid  = threadIdx.x;
    const int lane = tid & 63;
    const int wave = tid >> 6;
    const int node0 = blockIdx.x * NT;
    const float e1 = 1.0f + eps1p[0];

    // ---- Phase A ----
    for (int nn = 0; nn < NPW; nn++) {
        int node = node0 + wave * NPW + nn;
        float ax[4] = {0.f, 0.f, 0.f, 0.f};
        float ay[4] = {0.f, 0.f, 0.f, 0.f};
        if (node < N_NODES) {
            int beg = row_ptr[node], end = row_ptr[node + 1];
            for (int base = beg; base < end; base += 64) {
                int cnt = min(64, end - base);
                int srcs = (lane < cnt) ? csr_src[base + lane] : 0;
                int j = 0;
                for (; j + 8 <= cnt; j += 8) {
                    unsigned u[8];
#pragma unroll
                    for (int q = 0; q < 8; q++) {
                        int sq = __shfl(srcs, j + q, 64);
                        u[q] = xb[(size_t)sq * (IN_DIM / 2) + lane];
                    }
#pragma unroll
                    for (int q = 0; q < 8; q++) {
                        ax[q & 3] += __uint_as_float(u[q] << 16);
                        ay[q & 3] += __uint_as_float(u[q] & 0xffff0000u);
                    }
                }
                for (; j < cnt; j++) {
                    int sq = __shfl(srcs, j, 64);
                    unsigned uq = xb[(size_t)sq * (IN_DIM / 2) + lane];
                    ax[j & 3] += __uint_as_float(uq << 16);
                    ay[j & 3] += __uint_as_float(uq & 0xffff0000u);
                }
            }
            float2 xv = *(const float2*)(x + (size_t)node * IN_DIM + 2 * lane);
            ax[0] = fmaf(e1, xv.x, ax[0]);
            ay[0] = fmaf(e1, xv.y, ay[0]);
        }
        float zx = (ax[0] + ax[1]) + (ax[2] + ax[3]);
        float zy = (ay[0] + ay[1]) + (ay[2] + ay[3]);
        *(float2*)&z[wave * NPW + nn][2 * lane] = make_float2(zx, zy);
    }
    // no __syncthreads needed: each wave reads only its own z rows

    // ---- Phase B: GEMM1, 16 nodes x 4 columns per thread ----
    float4 b1v = *(const float4*)(b1 + 4 * lane);
    float4 acc[NPW];
#pragma unroll
    for (int nn = 0; nn < NPW; nn++) acc[nn] = b1v;

    for (int k4 = 0; k4 < IN_DIM / 4; k4++) {
        float4 w0 = *(const float4*)(W1 + (size_t)(4 * k4 + 0) * HID_DIM + 4 * lane);
        float4 w1 = *(const float4*)(W1 + (size_t)(4 * k4 + 1) * HID_DIM + 4 * lane);
        float4 w2 = *(const float4*)(W1 + (size_t)(4 * k4 + 2) * HID_DIM + 4 * lane);
        float4 w3 = *(const float4*)(W1 + (size_t)(4 * k4 + 3) * HID_DIM + 4 * lane);
#pragma unroll
        for (int nn = 0; nn < NPW; nn++) {
            float4 zv = *(const float4*)&z[wave * NPW + nn][4 * k4];  // broadcast
            acc[nn].x = fmaf(zv.x, w0.x, fmaf(zv.y, w1.x, fmaf(zv.z, w2.x, fmaf(zv.w, w3.x, acc[nn].x))));
            acc[nn].y = fmaf(zv.x, w0.y, fmaf(zv.y, w1.y, fmaf(zv.z, w2.y, fmaf(zv.w, w3.y, acc[nn].y))));
            acc[nn].z = fmaf(zv.x, w0.z, fmaf(zv.y, w1.z, fmaf(zv.z, w2.z, fmaf(zv.w, w3.z, acc[nn].z))));
            acc[nn].w = fmaf(zv.x, w0.w, fmaf(zv.y, w1.w, fmaf(zv.z, w2.w, fmaf(zv.w, w3.w, acc[nn].w))));
        }
    }

    // ---- Phase C: ReLU + GEMM2 + butterfly ----
    float2 w20 = *(const float2*)(W2 + (size_t)(4 * lane + 0) * OUT_DIM);
    float2 w21 = *(const float2*)(W2 + (size_t)(4 * lane + 1) * OUT_DIM);
    float2 w22 = *(const float2*)(W2 + (size_t)(4 * lane + 2) * OUT_DIM);
    float2 w23 = *(const float2*)(W2 + (size_t)(4 * lane + 3) * OUT_DIM);

#pragma unroll
    for (int nn = 0; nn < NPW; nn++) {
        float h0 = fmaxf(acc[nn].x, 0.f);
        float h1 = fmaxf(acc[nn].y, 0.f);
        float h2 = fmaxf(acc[nn].z, 0.f);
        float h3 = fmaxf(acc[nn].w, 0.f);
        float px = h0 * w20.x + h1 * w21.x + h2 * w22.x + h3 * w23.x;
        float py = h0 * w20.y + h1 * w21.y + h2 * w22.y + h3 * w23.y;
#pragma unroll
        for (int off = 32; off >= 1; off >>= 1) {
            px += __shfl_xor(px, off, 64);
            py += __shfl_xor(py, off, 64);
        }
        int node = node0 + wave * NPW + nn;
        if (lane == 0 && node < N_NODES) {
            p[(size_t)node * OUT_DIM + 0] = px;
            p[(size_t)node * OUT_DIM + 1] = py;
        }
    }
}

// ---------------------------------------------------------------------------
// Layer 2 pull: out[n] = (1+e2)*p[n] + b2 + sum_{src in row n} p[src]
// ---------------------------------------------------------------------------
__global__ __launch_bounds__(256) void k_out(
    const int* __restrict__ row_ptr, const int* __restrict__ csr_src,
    const float* __restrict__ p, const float* __restrict__ b2,
    const float* __restrict__ eps2p, float* __restrict__ out)
{
    int n = blockIdx.x * 256 + threadIdx.x;
    if (n >= N_NODES) return;
    float e2 = 1.0f + eps2p[0];
    int beg = row_ptr[n], end = row_ptr[n + 1];
    float sx = 0.f, sy = 0.f;
#pragma unroll 4
    for (int e = beg; e < end; e++) {
        int src = csr_src[e];
        float2 v = *(const float2*)(p + (size_t)src * OUT_DIM);
        sx += v.x; sy += v.y;
    }
    float2 pv = *(const float2*)(p + (size_t)n * OUT_DIM);
    out[(size_t)n * OUT_DIM + 0] = fmaf(e2, pv.x, sx) + b2[0];
    out[(size_t)n * OUT_DIM + 1] = fmaf(e2, pv.y, sy) + b2[1];
}

extern "C" void kernel_launch(void* const* d_in, const int* in_sizes, int n_in,
                              void* d_out, int out_size, void* d_ws, size_t ws_size,
                              hipStream_t stream)
{
    const float* x    = (const float*)d_in[0];
    const int*   ei   = (const int*)d_in[1];
    const float* W1   = (const float*)d_in[2];
    const float* b1   = (const float*)d_in[3];
    const float* W2   = (const float*)d_in[4];
    const float* b2   = (const float*)d_in[5];
    const float* eps1 = (const float*)d_in[6];
    const float* eps2 = (const float*)d_in[7];
    float* out = (float*)d_out;

    // workspace layout (16B-aligned segments)
    int* deg      = (int*)d_ws;             // 50048
    int* row_ptr  = deg + 50048;            // 50056 (N_NODES+1)
    int* cursor   = row_ptr + 50056;        // 50048
    int* partials = cursor + 50048;         // 256
    int* offsets  = partials + 256;         // 256
    int* csr_src  = offsets + 256;          // 800000
    float* p      = (float*)(csr_src + 800000);     // 100000
    unsigned* xb  = (unsigned*)(p + 100000);        // 3200000 (bf16x2)

    const int SCAN_BLKS = (N_NODES + 255) / 256;    // 196

    hipMemsetAsync(deg, 0, 50000 * sizeof(int), stream);

    k_cvt<<<(N_NODES * IN_DIM / 2 + 255) / 256, 256, 0, stream>>>(x, xb);
    k_hist<<<(N_EDGES + 255) / 256, 256, 0, stream>>>(ei, deg);
    k_scan_blk<<<SCAN_BLKS, 256, 0, stream>>>(deg, row_ptr, partials);
    k_scan_top<<<1, 256, 0, stream>>>(partials, offsets, SCAN_BLKS);
    k_scan_add<<<SCAN_BLKS, 256, 0, stream>>>(row_ptr, offsets, cursor);
    k_reorder<<<(N_EDGES + 255) / 256, 256, 0, stream>>>(ei, cursor, csr_src);
    k_gin1<<<(N_NODES + NT - 1) / NT, 128, 0, stream>>>(
        x, xb, row_ptr, csr_src, W1, b1, W2, eps1, p);
    k_out<<<(N_NODES + 255) / 256, 256, 0, stream>>>(row_ptr, csr_src, p, b2, eps2, out);
}